// Round 2
// baseline (100.181 us; speedup 1.0000x reference)
//
#include <hip/hip_runtime.h>
#include <float.h>

#define CHUNK 2048
#define SUB   2048   // cols per block = full chunk (R11-best: one resident cohort)
#define MBLK  128    // rows per block = 4 waves x one 32-row strip

typedef __attribute__((ext_vector_type(8)))  short short8;
typedef __attribute__((ext_vector_type(16))) float f32x16;

// ---- bf16 split helpers (RN-even; inputs finite) ----
static __device__ __forceinline__ unsigned short f2bf(float f) {
    unsigned u = __float_as_uint(f);
    return (unsigned short)((u + 0x7FFFu + ((u >> 16) & 1u)) >> 16);
}
static __device__ __forceinline__ float bf2f(unsigned short s) {
    return __uint_as_float(((unsigned)s) << 16);
}

// ---- Pass 0: pack K=16 bf16 records ----
// A-record (p1 point):  [ph(3), pl(3), ph(3), pl(3), sp_hi, sp_lo, 1, 1]
// B-record (p2 point):  [uh(3), uh(3), ul(3), ul(3), 1, 1, sq_hi, sq_lo]
// Mutually transposable; dot(A_k,B_k) = sp + sq - 2 p.q with either side as
// the MFMA A-operand. Verified R5-R13 (absmax 0) in both orientations.
__global__ void pack_kernel(const float* __restrict__ p1,
                            const float* __restrict__ p2, int n1, int n2,
                            unsigned short* __restrict__ Arec,
                            unsigned short* __restrict__ Brec)
{
    int i = blockIdx.x * blockDim.x + threadIdx.x;
    if (i >= n1 + n2) return;
    const bool isA = (i < n1);
    const float* s = isA ? p1 : p2;
    const int j = isA ? i : i - n1;
    float x = s[3 * j + 0], y = s[3 * j + 1], z = s[3 * j + 2];

    unsigned short r[16];
    if (isA) {
        unsigned short hx = f2bf(x), hy = f2bf(y), hz = f2bf(z);
        unsigned short lx = f2bf(x - bf2f(hx)), ly = f2bf(y - bf2f(hy)),
                       lz = f2bf(z - bf2f(hz));
        float sp = fmaf(x, x, fmaf(y, y, z * z));
        unsigned short sh = f2bf(sp), sl = f2bf(sp - bf2f(sh));
        r[0]=hx; r[1]=hy; r[2]=hz;  r[3]=lx; r[4]=ly; r[5]=lz;
        r[6]=hx; r[7]=hy; r[8]=hz;  r[9]=lx; r[10]=ly; r[11]=lz;
        r[12]=sh; r[13]=sl; r[14]=0x3F80; r[15]=0x3F80;
        unsigned short* dst = Arec + (size_t)j * 16;
#pragma unroll
        for (int t = 0; t < 16; ++t) dst[t] = r[t];
    } else {
        float ux = -2.0f * x, uy = -2.0f * y, uz = -2.0f * z;
        unsigned short hx = f2bf(ux), hy = f2bf(uy), hz = f2bf(uz);
        unsigned short lx = f2bf(ux - bf2f(hx)), ly = f2bf(uy - bf2f(hy)),
                       lz = f2bf(uz - bf2f(hz));
        float sq = fmaf(x, x, fmaf(y, y, z * z));
        unsigned short sh = f2bf(sq), sl = f2bf(sq - bf2f(sh));
        r[0]=hx; r[1]=hy; r[2]=hz;  r[3]=hx; r[4]=hy; r[5]=hz;
        r[6]=lx; r[7]=ly; r[8]=lz;  r[9]=lx; r[10]=ly; r[11]=lz;
        r[12]=0x3F80; r[13]=0x3F80; r[14]=sh; r[15]=sl;
        unsigned short* dst = Brec + (size_t)j * 16;
#pragma unroll
        for (int t = 0; t < 16; ++t) dst[t] = r[t];
    }
}

// ---- rowmin tournament across 32 lanes (verified R6-R13, absmax 0) ----
static __device__ __forceinline__ float tourney16(float rm[16], int l31)
{
#pragma unroll
    for (int r = 0; r < 8; ++r) {
        float lo = fminf(rm[r],     __shfl_xor(rm[r],     16));
        float hi = fminf(rm[r + 8], __shfl_xor(rm[r + 8], 16));
        rm[r] = (l31 & 16) ? hi : lo;
    }
#pragma unroll
    for (int r = 0; r < 4; ++r) {
        float lo = fminf(rm[r],     __shfl_xor(rm[r],     8));
        float hi = fminf(rm[r + 4], __shfl_xor(rm[r + 4], 8));
        rm[r] = (l31 & 8) ? hi : lo;
    }
#pragma unroll
    for (int r = 0; r < 2; ++r) {
        float lo = fminf(rm[r],     __shfl_xor(rm[r],     4));
        float hi = fminf(rm[r + 2], __shfl_xor(rm[r + 2], 4));
        rm[r] = (l31 & 4) ? hi : lo;
    }
    {
        float lo = fminf(rm[0], __shfl_xor(rm[0], 2));
        float hi = fminf(rm[1], __shfl_xor(rm[1], 2));
        rm[0] = (l31 & 2) ? hi : lo;
    }
    return fminf(rm[0], __shfl_xor(rm[0], 1));
}

// ---- Pass 1: rowmin MFMA kernel + fused mean reduction ----
// R14 = R11-best hot loop (direct global loads, no barriers) + R13's fused
// epilogue (pass2 folded in; block-sum + one atomicAdd per block).
// R13 post-mortem: LDS double-buffer staging regressed chamfer ~30->43 us
// (vmcnt(0)+barrier drain every 8 MFMAs = the 2-phase stall; the direct-load
// loop's 64-deep independent-load pipeline already hides latency). Fusion
// saved ~6 us. This round isolates fusion on the measured-best loop.
// Falsified ledger: LDS staging (R13), 2x-work single-pass (R5), LDS/global
// atomics in hot loop (R5/R6), plain stores (R7), prefetch depth 1/2
// (R8/R10), cohort turnover (R11), load-count/TLP trades (R9/R12).
// NOTE: fused mean assumes SUB == CHUNK (gpc = 1).
// v_mfma_f32_32x32x16_bf16: A[m=lane&31][k=half*8+j], B[k=half*8+j][n=lane&31],
//   C/D: col=lane&31, row=(reg&3)+8*(reg>>2)+4*half.
__global__ __launch_bounds__(256, 8)
void chamfer_mfma(const unsigned short* __restrict__ Arec,
                  const unsigned short* __restrict__ Brec,
                  float* __restrict__ out,
                  int n1, int n2, float s2, float s1)
{
    __shared__ float wred[4];

    const int dir = blockIdx.z;
    const unsigned short* __restrict__ Ap = dir ? Brec : Arec;
    const unsigned short* __restrict__ Bp = dir ? Arec : Brec;
    const float scale = dir ? s1 : s2;
    const int rows_n = dir ? n2 : n1;
    const int cols_n = dir ? n1 : n2;

    const int tid  = threadIdx.x;
    const int g    = blockIdx.x;          // row group (128 rows of A-side)
    const int yb   = blockIdx.y;          // col chunk (2048 cols of B-side)
    if (g * MBLK >= rows_n || yb * SUB >= cols_n) return;  // uniform

    const int lane = tid & 63;
    const int w    = tid >> 6;
    const int half = lane >> 5;
    const int l31  = lane & 31;

    // A fragment (fixed per wave): one 32-row strip
    const int rA = g * MBLK + w * 32 + l31;
    short8 aA = *(const short8*)(Ap + (size_t)rA * 16 + half * 8);

    const unsigned short* bp =
        Bp + (size_t)(yb * SUB + l31) * 16 + half * 8;

    const f32x16 z16 = {0,0,0,0, 0,0,0,0, 0,0,0,0, 0,0,0,0};
    float rm[16];
#pragma unroll
    for (int r = 0; r < 16; ++r) rm[r] = FLT_MAX;

    const int NT = SUB / 32;   // 64 tiles
    for (int t = 0; t < NT; ++t) {
        short8 b = *(const short8*)(bp + (size_t)t * 512);
        f32x16 d = __builtin_amdgcn_mfma_f32_32x32x16_bf16(aA, b, z16, 0, 0, 0);
#pragma unroll
        for (int r = 0; r < 16; ++r) rm[r] = fminf(rm[r], d[r]);
    }

    // ---- tournament + fused mean: block sum, one atomicAdd per block ----
    float v = tourney16(rm, l31);
    float c = ((l31 & 1) == 0) ? fmaxf(v, 0.0f) : 0.0f;  // 32 rows/wave counted once
#pragma unroll
    for (int off = 32; off > 0; off >>= 1) c += __shfl_down(c, off);
    if (lane == 0) wred[w] = c;
    __syncthreads();
    if (tid == 0)
        atomicAdd(out, (wred[0] + wred[1] + wred[2] + wred[3]) * scale);
}

// ---- Fallback (ws too small / odd shapes): R1's verified pure-VALU kernel ----
#define FB_RPT  2
#define FB_TILE (256 * FB_RPT)
__global__ __launch_bounds__(256, 2)
void chamfer_valu(const float* __restrict__ p1, const float* __restrict__ p2,
                  int n1, int n2, float* __restrict__ out)
{
    __shared__ float4 q[CHUNK];
    __shared__ float wsum[4];
    const int dir = blockIdx.z;
    const float* __restrict__ src = dir ? p2 : p1;
    const float* __restrict__ ref = dir ? p1 : p2;
    const int nsrc = dir ? n2 : n1;
    const int m    = dir ? n1 : n2;
    const int nchunks = nsrc / CHUNK;
    const int c = blockIdx.y;
    const int tile0 = blockIdx.x * FB_TILE;
    if (c >= nchunks || tile0 >= m) return;
    const float scale = 1.0f / ((float)nchunks * (float)m);
    const float* __restrict__ chunk = src + (size_t)c * CHUNK * 3;
    for (int k = threadIdx.x; k < CHUNK; k += 256) {
        float x = chunk[3*k], y = chunk[3*k+1], z = chunk[3*k+2];
        q[k] = make_float4(x, y, z, fmaf(x, x, fmaf(y, y, z * z)));
    }
    __syncthreads();
    float px[FB_RPT], py[FB_RPT], pz[FB_RPT], sp[FB_RPT], mna[FB_RPT], mnb[FB_RPT];
    bool valid[FB_RPT];
#pragma unroll
    for (int r = 0; r < FB_RPT; ++r) {
        int j = tile0 + threadIdx.x + r * 256;
        valid[r] = (j < m);
        int jj = valid[r] ? j : 0;
        float x = ref[3*jj], y = ref[3*jj+1], z = ref[3*jj+2];
        px[r] = -2.0f*x; py[r] = -2.0f*y; pz[r] = -2.0f*z;
        sp[r] = fmaf(x, x, fmaf(y, y, z * z));
        mna[r] = FLT_MAX; mnb[r] = FLT_MAX;
    }
#pragma unroll 2
    for (int k = 0; k < CHUNK; k += 2) {
        float4 qa = q[k], qb = q[k+1];
#pragma unroll
        for (int r = 0; r < FB_RPT; ++r) {
            mna[r] = fminf(mna[r], fmaf(px[r], qa.x, fmaf(py[r], qa.y, fmaf(pz[r], qa.z, qa.w))));
            mnb[r] = fminf(mnb[r], fmaf(px[r], qb.x, fmaf(py[r], qb.y, fmaf(pz[r], qb.z, qb.w))));
        }
    }
    float sum = 0.0f;
#pragma unroll
    for (int r = 0; r < FB_RPT; ++r)
        if (valid[r]) sum += fmaxf(fminf(mna[r], mnb[r]) + sp[r], 0.0f);
#pragma unroll
    for (int off = 32; off > 0; off >>= 1) sum += __shfl_down(sum, off);
    if ((threadIdx.x & 63) == 0) wsum[threadIdx.x >> 6] = sum;
    __syncthreads();
    if (threadIdx.x == 0)
        atomicAdd(out, (wsum[0]+wsum[1]+wsum[2]+wsum[3]) * scale);
}

extern "C" void kernel_launch(void* const* d_in, const int* in_sizes, int n_in,
                              void* d_out, int out_size, void* d_ws, size_t ws_size,
                              hipStream_t stream)
{
    const float* p1 = (const float*)d_in[0];  // output_pc [N,3]
    const float* p2 = (const float*)d_in[1];  // gt_pc     [M,3]
    float* out = (float*)d_out;
    const int n1 = in_sizes[0] / 3;
    const int n2 = in_sizes[1] / 3;

    const int nc1 = n1 / CHUNK, nc2 = n2 / CHUNK;

    unsigned short* Arec = (unsigned short*)d_ws;            // n1*32 B
    unsigned short* Brec = Arec + (size_t)n1 * 16;           // n2*32 B
    const size_t need = (size_t)(n1 + n2) * 32;

    const bool shapes_ok = (n1 % CHUNK == 0) && (n2 % CHUNK == 0) &&
                           (n1 % MBLK == 0) && (n2 % MBLK == 0) &&
                           (n1 % SUB == 0) && (n2 % SUB == 0);

    if (shapes_ok && ws_size >= need) {
        pack_kernel<<<(n1 + n2 + 255) / 256, 256, 0, stream>>>(
            p1, p2, n1, n2, Arec, Brec);
        const int gx = max(n1, n2) / MBLK;
        const int gy = max(n1, n2) / SUB;
        dim3 grid(gx, gy, 2);
        chamfer_mfma<<<grid, 256, 0, stream>>>(
            Arec, Brec, out, n1, n2,
            1.0f / ((float)nc2 * (float)n1), 1.0f / ((float)nc1 * (float)n2));
    } else {
        const int t1 = (n2 + FB_TILE - 1) / FB_TILE;
        const int t2 = (n1 + FB_TILE - 1) / FB_TILE;
        dim3 grid(max(t1, t2), max(nc1, nc2), 2);
        chamfer_valu<<<grid, 256, 0, stream>>>(p1, p2, n1, n2, out);
    }
}

// Round 3
// 81.264 us; speedup vs baseline: 1.2328x; 1.2328x over previous
//
#include <hip/hip_runtime.h>
#include <float.h>

#define CHUNK 2048
#define SUB   2048   // cols per block = full chunk (one resident cohort)
#define MBLK  128    // rows per block = 4 waves x one 32-row strip
#define GRP   256    // B records staged per LDS group (8 KB)
#define NGRP  (SUB / GRP)

typedef __attribute__((ext_vector_type(8)))  short short8;
typedef __attribute__((ext_vector_type(16))) float f32x16;

// ---- bf16 split helpers (RN-even; inputs finite) ----
static __device__ __forceinline__ unsigned short f2bf(float f) {
    unsigned u = __float_as_uint(f);
    return (unsigned short)((u + 0x7FFFu + ((u >> 16) & 1u)) >> 16);
}
static __device__ __forceinline__ float bf2f(unsigned short s) {
    return __uint_as_float(((unsigned)s) << 16);
}

// ---- async global->LDS, 16B per lane, linear (wave-uniform LDS base) ----
static __device__ __forceinline__ void gld16(const void* g, void* l) {
    __builtin_amdgcn_global_load_lds(
        (const __attribute__((address_space(1))) void*)g,
        (__attribute__((address_space(3))) void*)l, 16, 0, 0);
}

// ---- Pass 0: pack K=16 bf16 records ----
// A-record (p1 point):  [ph(3), pl(3), ph(3), pl(3), sp_hi, sp_lo, 1, 1]
// B-record (p2 point):  [uh(3), uh(3), ul(3), ul(3), 1, 1, sq_hi, sq_lo]
// Mutually transposable; dot(A_k,B_k) = sp + sq - 2 p.q with either side as
// the MFMA A-operand. Verified R5-R14 (absmax 0) in both orientations.
__global__ void pack_kernel(const float* __restrict__ p1,
                            const float* __restrict__ p2, int n1, int n2,
                            unsigned short* __restrict__ Arec,
                            unsigned short* __restrict__ Brec)
{
    int i = blockIdx.x * blockDim.x + threadIdx.x;
    if (i >= n1 + n2) return;
    const bool isA = (i < n1);
    const float* s = isA ? p1 : p2;
    const int j = isA ? i : i - n1;
    float x = s[3 * j + 0], y = s[3 * j + 1], z = s[3 * j + 2];

    unsigned short r[16];
    if (isA) {
        unsigned short hx = f2bf(x), hy = f2bf(y), hz = f2bf(z);
        unsigned short lx = f2bf(x - bf2f(hx)), ly = f2bf(y - bf2f(hy)),
                       lz = f2bf(z - bf2f(hz));
        float sp = fmaf(x, x, fmaf(y, y, z * z));
        unsigned short sh = f2bf(sp), sl = f2bf(sp - bf2f(sh));
        r[0]=hx; r[1]=hy; r[2]=hz;  r[3]=lx; r[4]=ly; r[5]=lz;
        r[6]=hx; r[7]=hy; r[8]=hz;  r[9]=lx; r[10]=ly; r[11]=lz;
        r[12]=sh; r[13]=sl; r[14]=0x3F80; r[15]=0x3F80;
        unsigned short* dst = Arec + (size_t)j * 16;
#pragma unroll
        for (int t = 0; t < 16; ++t) dst[t] = r[t];
    } else {
        float ux = -2.0f * x, uy = -2.0f * y, uz = -2.0f * z;
        unsigned short hx = f2bf(ux), hy = f2bf(uy), hz = f2bf(uz);
        unsigned short lx = f2bf(ux - bf2f(hx)), ly = f2bf(uy - bf2f(hy)),
                       lz = f2bf(uz - bf2f(hz));
        float sq = fmaf(x, x, fmaf(y, y, z * z));
        unsigned short sh = f2bf(sq), sl = f2bf(sq - bf2f(sh));
        r[0]=hx; r[1]=hy; r[2]=hz;  r[3]=hx; r[4]=hy; r[5]=hz;
        r[6]=lx; r[7]=ly; r[8]=lz;  r[9]=lx; r[10]=ly; r[11]=lz;
        r[12]=0x3F80; r[13]=0x3F80; r[14]=sh; r[15]=sl;
        unsigned short* dst = Brec + (size_t)j * 16;
#pragma unroll
        for (int t = 0; t < 16; ++t) dst[t] = r[t];
    }
}

// ---- rowmin tournament across 32 lanes (verified R6-R14, absmax 0) ----
static __device__ __forceinline__ float tourney16(float rm[16], int l31)
{
#pragma unroll
    for (int r = 0; r < 8; ++r) {
        float lo = fminf(rm[r],     __shfl_xor(rm[r],     16));
        float hi = fminf(rm[r + 8], __shfl_xor(rm[r + 8], 16));
        rm[r] = (l31 & 16) ? hi : lo;
    }
#pragma unroll
    for (int r = 0; r < 4; ++r) {
        float lo = fminf(rm[r],     __shfl_xor(rm[r],     8));
        float hi = fminf(rm[r + 4], __shfl_xor(rm[r + 4], 8));
        rm[r] = (l31 & 8) ? hi : lo;
    }
#pragma unroll
    for (int r = 0; r < 2; ++r) {
        float lo = fminf(rm[r],     __shfl_xor(rm[r],     4));
        float hi = fminf(rm[r + 2], __shfl_xor(rm[r + 2], 4));
        rm[r] = (l31 & 4) ? hi : lo;
    }
    {
        float lo = fminf(rm[0], __shfl_xor(rm[0], 2));
        float hi = fminf(rm[1], __shfl_xor(rm[1], 2));
        rm[0] = (l31 & 2) ? hi : lo;
    }
    return fminf(rm[0], __shfl_xor(rm[0], 1));
}

// ---- Pass 1: rowmin MFMA kernel, LDS-staged B, per-block partial sum ----
// R15 = R13's staged loop (measured 5.5 us faster than direct via the clean
// R13-vs-R14 cross-A/B: identical epilogues, 94.7 vs 100.2) + store-based
// epilogue. R14 post-mortem: the fused SINGLE-ADDRESS atomicAdd cost ~+20 us
// (2048 same-line device-scope RMWs arriving in a burst -> serialized tail;
// chamfer counter showed 51 us vs ~30 baseline with identical hot loop).
// Fix: each block plain-stores its partial into bsum[bid]; a 1-block
// final_reduce sums 2048 floats -> out.
// Falsified ledger: single-address fused atomic (R14, +20us), 2x-work
// single-pass (R5), LDS/global atomics in hot loop (R5/R6), plain stores of
// full rowmin matrix + separate pass2 (baseline, +5us vs fusion), prefetch
// depth 1/2 (R8/R10), cohort turnover (R11), load-count/TLP trades (R9/R12).
// NOTE: fused mean assumes SUB == CHUNK (gpc = 1).
// v_mfma_f32_32x32x16_bf16: A[m=lane&31][k=half*8+j], B[k=half*8+j][n=lane&31],
//   C/D: col=lane&31, row=(reg&3)+8*(reg>>2)+4*half.
__global__ __launch_bounds__(256, 8)
void chamfer_mfma(const unsigned short* __restrict__ Arec,
                  const unsigned short* __restrict__ Brec,
                  float* __restrict__ bsum,
                  int n1, int n2, float s2, float s1)
{
    __shared__ alignas(16) unsigned short sb[2][GRP * 16]; // 2 x 8 KB
    __shared__ float wred[4];

    const int dir = blockIdx.z;
    const unsigned short* __restrict__ Ap = dir ? Brec : Arec;
    const unsigned short* __restrict__ Bp = dir ? Arec : Brec;
    const float scale = dir ? s1 : s2;
    const int rows_n = dir ? n2 : n1;
    const int cols_n = dir ? n1 : n2;

    const int tid  = threadIdx.x;
    const int g    = blockIdx.x;          // row group (128 rows of A-side)
    const int yb   = blockIdx.y;          // col chunk (2048 cols of B-side)
    const int bid  = g + gridDim.x * (yb + gridDim.y * dir);
    if (g * MBLK >= rows_n || yb * SUB >= cols_n) {   // uniform per block
        if (tid == 0) bsum[bid] = 0.0f;
        return;
    }

    const int lane = tid & 63;
    const int w    = tid >> 6;
    const int half = lane >> 5;
    const int l31  = lane & 31;

    // A fragment (fixed per wave): one 32-row strip
    const int rA = g * MBLK + w * 32 + l31;
    short8 aA = *(const short8*)(Ap + (size_t)rA * 16 + half * 8);

    const char* Bbytes = (const char*)(Bp + (size_t)(yb * SUB) * 16);

    float rm[16];
#pragma unroll
    for (int r = 0; r < 16; ++r) rm[r] = FLT_MAX;
    const f32x16 z16 = {0,0,0,0, 0,0,0,0, 0,0,0,0, 0,0,0,0};

    // prologue: stage group 0 (8 KB = 2 x 16B per thread, linear)
    {
        const char* gp = Bbytes + tid * 16;
        char* lp = (char*)&sb[0][0] + w * 1024;
        gld16(gp, lp);
        gld16(gp + 4096, lp + 4096);
    }
    __syncthreads();   // compiler emits vmcnt(0) drain before barrier

    for (int gr = 0; gr < NGRP; ++gr) {
        const int cur = gr & 1;
        if (gr + 1 < NGRP) {           // issue next-group stage first
            const char* gp = Bbytes + (size_t)(gr + 1) * 8192 + tid * 16;
            char* lp = (char*)&sb[cur ^ 1][0] + w * 1024;
            gld16(gp, lp);
            gld16(gp + 4096, lp + 4096);
        }
        const unsigned short* lb = &sb[cur][l31 * 16 + half * 8];
#pragma unroll
        for (int tt = 0; tt < GRP / 32; ++tt) {
            short8 b = *(const short8*)(lb + tt * 512);   // ds_read_b128
            f32x16 d = __builtin_amdgcn_mfma_f32_32x32x16_bf16(aA, b, z16, 0, 0, 0);
#pragma unroll
            for (int r = 0; r < 16; ++r) rm[r] = fminf(rm[r], d[r]);
        }
        __syncthreads();               // one drain+barrier per group
    }

    // ---- tournament + block partial sum, one plain store per block ----
    float v = tourney16(rm, l31);
    float c = ((l31 & 1) == 0) ? fmaxf(v, 0.0f) : 0.0f;  // 32 rows/wave counted once
#pragma unroll
    for (int off = 32; off > 0; off >>= 1) c += __shfl_down(c, off);
    if (lane == 0) wred[w] = c;
    __syncthreads();
    if (tid == 0)
        bsum[bid] = (wred[0] + wred[1] + wred[2] + wred[3]) * scale;
}

// ---- Pass 2: reduce per-block partials (n ~ 2048 floats) ----
__global__ __launch_bounds__(256)
void final_reduce(const float* __restrict__ bsum, float* __restrict__ out, int n)
{
    __shared__ float wred[4];
    float s = 0.0f;
    for (int i = threadIdx.x; i < n; i += 256) s += bsum[i];
#pragma unroll
    for (int off = 32; off > 0; off >>= 1) s += __shfl_down(s, off);
    const int lane = threadIdx.x & 63, w = threadIdx.x >> 6;
    if (lane == 0) wred[w] = s;
    __syncthreads();
    if (threadIdx.x == 0)
        out[0] = wred[0] + wred[1] + wred[2] + wred[3];
}

// ---- Fallback (ws too small / odd shapes): R1's verified pure-VALU kernel ----
#define FB_RPT  2
#define FB_TILE (256 * FB_RPT)
__global__ __launch_bounds__(256, 2)
void chamfer_valu(const float* __restrict__ p1, const float* __restrict__ p2,
                  int n1, int n2, float* __restrict__ out)
{
    __shared__ float4 q[CHUNK];
    __shared__ float wsum[4];
    const int dir = blockIdx.z;
    const float* __restrict__ src = dir ? p2 : p1;
    const float* __restrict__ ref = dir ? p1 : p2;
    const int nsrc = dir ? n2 : n1;
    const int m    = dir ? n1 : n2;
    const int nchunks = nsrc / CHUNK;
    const int c = blockIdx.y;
    const int tile0 = blockIdx.x * FB_TILE;
    if (c >= nchunks || tile0 >= m) return;
    const float scale = 1.0f / ((float)nchunks * (float)m);
    const float* __restrict__ chunk = src + (size_t)c * CHUNK * 3;
    for (int k = threadIdx.x; k < CHUNK; k += 256) {
        float x = chunk[3*k], y = chunk[3*k+1], z = chunk[3*k+2];
        q[k] = make_float4(x, y, z, fmaf(x, x, fmaf(y, y, z * z)));
    }
    __syncthreads();
    float px[FB_RPT], py[FB_RPT], pz[FB_RPT], sp[FB_RPT], mna[FB_RPT], mnb[FB_RPT];
    bool valid[FB_RPT];
#pragma unroll
    for (int r = 0; r < FB_RPT; ++r) {
        int j = tile0 + threadIdx.x + r * 256;
        valid[r] = (j < m);
        int jj = valid[r] ? j : 0;
        float x = ref[3*jj], y = ref[3*jj+1], z = ref[3*jj+2];
        px[r] = -2.0f*x; py[r] = -2.0f*y; pz[r] = -2.0f*z;
        sp[r] = fmaf(x, x, fmaf(y, y, z * z));
        mna[r] = FLT_MAX; mnb[r] = FLT_MAX;
    }
#pragma unroll 2
    for (int k = 0; k < CHUNK; k += 2) {
        float4 qa = q[k], qb = q[k+1];
#pragma unroll
        for (int r = 0; r < FB_RPT; ++r) {
            mna[r] = fminf(mna[r], fmaf(px[r], qa.x, fmaf(py[r], qa.y, fmaf(pz[r], qa.z, qa.w))));
            mnb[r] = fminf(mnb[r], fmaf(px[r], qb.x, fmaf(py[r], qb.y, fmaf(pz[r], qb.z, qb.w))));
        }
    }
    float sum = 0.0f;
#pragma unroll
    for (int r = 0; r < FB_RPT; ++r)
        if (valid[r]) sum += fmaxf(fminf(mna[r], mnb[r]) + sp[r], 0.0f);
#pragma unroll
    for (int off = 32; off > 0; off >>= 1) sum += __shfl_down(sum, off);
    if ((threadIdx.x & 63) == 0) wsum[threadIdx.x >> 6] = sum;
    __syncthreads();
    if (threadIdx.x == 0)
        atomicAdd(out, (wsum[0]+wsum[1]+wsum[2]+wsum[3]) * scale);
}

extern "C" void kernel_launch(void* const* d_in, const int* in_sizes, int n_in,
                              void* d_out, int out_size, void* d_ws, size_t ws_size,
                              hipStream_t stream)
{
    const float* p1 = (const float*)d_in[0];  // output_pc [N,3]
    const float* p2 = (const float*)d_in[1];  // gt_pc     [M,3]
    float* out = (float*)d_out;
    const int n1 = in_sizes[0] / 3;
    const int n2 = in_sizes[1] / 3;

    const int nc1 = n1 / CHUNK, nc2 = n2 / CHUNK;

    const int gx = max(n1, n2) / MBLK;
    const int gy = max(n1, n2) / SUB;
    const int nblocks = gx * gy * 2;

    unsigned short* Arec = (unsigned short*)d_ws;            // n1*32 B
    unsigned short* Brec = Arec + (size_t)n1 * 16;           // n2*32 B
    float* bsum = (float*)(Brec + (size_t)n2 * 16);          // nblocks*4 B
    const size_t need = (size_t)(n1 + n2) * 32 + (size_t)nblocks * 4;

    const bool shapes_ok = (n1 % CHUNK == 0) && (n2 % CHUNK == 0) &&
                           (n1 % MBLK == 0) && (n2 % MBLK == 0) &&
                           (n1 % SUB == 0) && (n2 % SUB == 0);

    if (shapes_ok && ws_size >= need) {
        pack_kernel<<<(n1 + n2 + 255) / 256, 256, 0, stream>>>(
            p1, p2, n1, n2, Arec, Brec);
        dim3 grid(gx, gy, 2);
        chamfer_mfma<<<grid, 256, 0, stream>>>(
            Arec, Brec, bsum, n1, n2,
            1.0f / ((float)nc2 * (float)n1), 1.0f / ((float)nc1 * (float)n2));
        final_reduce<<<1, 256, 0, stream>>>(bsum, out, nblocks);
    } else {
        const int t1 = (n2 + FB_TILE - 1) / FB_TILE;
        const int t2 = (n1 + FB_TILE - 1) / FB_TILE;
        dim3 grid(max(t1, t2), max(nc1, nc2), 2);
        chamfer_valu<<<grid, 256, 0, stream>>>(p1, p2, n1, n2, out);
    }
}